// Round 3
// baseline (632.682 us; speedup 1.0000x reference)
//
#include <hip/hip_runtime.h>

// WaveguideOutputSimulation: 2D Helmholtz + PML solve.
// BABE block-Thomas (2 waves, serial depth 25).
// R9: gj48 via LDS broadcast, simplified single-phase scheme (R8's two-phase
// d->U pipeline NaN'd; this removes it). Per pivot: row owners write RAW
// pivot row R' (+1 fixup at pivot entry), col owners write RAW pivot col C'
// (pv'-1 fixup), owner writes raw pv'. All lanes read back, compute
// d'=1/pv' and U'[i]=d'*C'[i] locally (d'*(pv'-1)=1-d' gives the U fixup).
// Rank-1 update m -= U*R performs the complete in-place pivot (identity
// verified: general m-c*d*r, pivot row d*r, pivot col -d*c, pivot d).
// Broadcast buffers double-buffered by pivot parity (kills WAR across
// iterations); sched_barrier(0) pins write->read->bulk issue order; reads
// issue before the 25-element bulk update so LDS latency hides under FMAs.

#define NXY 48
#define NN  2304

typedef float v2 __attribute__((ext_vector_type(2)));
typedef float v4 __attribute__((ext_vector_type(4)));
typedef double2 zplx;

__device__ __forceinline__ v2 mk2(float x, float y){ v2 r; r.x=x; r.y=y; return r; }
__device__ __forceinline__ v2 bcx(v2 a){ return __builtin_shufflevector(a,a,0,0); }
__device__ __forceinline__ v2 bcy(v2 a){ return __builtin_shufflevector(a,a,1,1); }
// (-a.y, a.x)
__device__ __forceinline__ v2 jswp(v2 a){ v2 r = __builtin_shufflevector(a,a,1,0); r.x = -r.x; return r; }
// a*b (complex) = a.x*(b.x,b.y) + a.y*(-b.y,b.x)
__device__ __forceinline__ v2 cmul(v2 a, v2 b){
    return __builtin_elementwise_fma(bcx(a), b, bcy(a)*jswp(b));
}
// c + a*b
__device__ __forceinline__ v2 cfma_(v2 c, v2 a, v2 b){
    return __builtin_elementwise_fma(bcx(a), b, __builtin_elementwise_fma(bcy(a), jswp(b), c));
}
// c - a*b
__device__ __forceinline__ v2 cfms(v2 c, v2 a, v2 b){
    return __builtin_elementwise_fma(-bcx(a), b, __builtin_elementwise_fma(-bcy(a), jswp(b), c));
}
__device__ __forceinline__ v2 cinv(v2 a){
    float s = 1.0f/fmaf(a.x,a.x, a.y*a.y);
    return mk2(a.x*s, -a.y*s);
}
__device__ __forceinline__ v2 shfl_c(v2 a, int lane){
    return mk2(__shfl(a.x, lane), __shfl(a.y, lane));
}
__device__ __forceinline__ v2 bfly_c(v2 v){
    v.x += __shfl_xor(v.x,1); v.y += __shfl_xor(v.y,1);
    v.x += __shfl_xor(v.x,2); v.y += __shfl_xor(v.y,2);
    v.x += __shfl_xor(v.x,4); v.y += __shfl_xor(v.y,4);
    return v;
}

// ---- fp64 setup math (once per launch, negligible) ----
__device__ __forceinline__ zplx zmul64(zplx a, zplx b){
    return make_double2(a.x*b.x - a.y*b.y, a.x*b.y + a.y*b.x);
}
__device__ __forceinline__ zplx zadd64(zplx a, zplx b){ return make_double2(a.x+b.x, a.y+b.y); }
__device__ __forceinline__ zplx zneg64(zplx a){ return make_double2(-a.x, -a.y); }
__device__ __forceinline__ zplx zinv64(zplx a){
    double s = 1.0/(a.x*a.x + a.y*a.y);
    return make_double2(a.x*s, -a.y*s);
}
__device__ __forceinline__ zplx fun_s(double u){
    const double sig = 0.8*4.0*40.0/(2.0*3.1415926);
    double u3 = u*u*u;
    return make_double2(1.0 + 14.0*u3, sig*u3);
}
__device__ __forceinline__ zplx s_half_at(int j){
    if (j <= 8)  return fun_s((8.5 - (double)j)/9.0);
    if (j >= 40) return fun_s(((double)(j-40) + 0.5)/9.0);
    return make_double2(1.0, 0.0);
}
__device__ __forceinline__ zplx s_int_at(int j){
    if (j <= 7)  return fun_s((8.0 - (double)j)/9.0);
    if (j >= 40) return fun_s(((double)(j-40) + 1.0)/9.0);
    return make_double2(1.0, 0.0);
}

// LDS-broadcast in-wave Gauss-Jordan of the distributed 48x48
// (8x8 lanes x 6x6 tile; lane (lr,lc) holds global (6lr+i, 6lc+j)).
// Pivot p=(kr,kj) global 6kr+kj. Identity per pivot (all verified):
//   R[j] = raw pivot row, R[p] = pv+1
//   U[i] = d*rawcol,      U[p] = d*(pv-1) = 1-d   (col buffer stores pv-1)
//   m -= U x R  ==>  general: m - c*d*r ; prow -> d*r ; pcol -> -d*c ; p -> d.
// Per iteration: early-update next pivot's tile row/col nj; owners write
// raw R'/C'/pv' (7 DS writes); readers issue 7 DS reads; 25-element bulk
// update hides the read latency; unpack + cinv + 6 cmul tail.
__device__ __forceinline__ void gj48_lds(v2 (&m)[6][6], const int lr, const int lc,
                                         v4* Rb, v4* Cb, v2* Dp){
    v2 R[6], U[6];
    // ---- prologue: pivot 0 broadcasts (buffer 0) ----
    if (lr==0){
        #pragma unroll
        for (int jp=0;jp<3;++jp){
            v2 a = m[0][2*jp], b = m[0][2*jp+1];
            if (lc==0 && jp==0) a.x += 1.f;       // R[p0] = pv+1
            v4 t; t.x=a.x; t.y=a.y; t.z=b.x; t.w=b.y;
            Rb[3*lc+jp] = t;
        }
    }
    if (lc==0){
        #pragma unroll
        for (int ip=0;ip<3;++ip){
            v2 a = m[2*ip][0], b = m[2*ip+1][0];
            if (lr==0 && ip==0) a.x -= 1.f;       // C[p0] = pv-1
            v4 t; t.x=a.x; t.y=a.y; t.z=b.x; t.w=b.y;
            Cb[3*lr+ip] = t;
        }
        if (lr==0) Dp[0] = m[0][0];
    }
    __builtin_amdgcn_sched_barrier(0);
    {
        v2 pvd = Dp[0];
        v4 rt0 = Rb[3*lc+0], rt1 = Rb[3*lc+1], rt2 = Rb[3*lc+2];
        v4 ct0 = Cb[3*lr+0], ct1 = Cb[3*lr+1], ct2 = Cb[3*lr+2];
        v2 d = cinv(pvd);
        R[0]=mk2(rt0.x,rt0.y); R[1]=mk2(rt0.z,rt0.w);
        R[2]=mk2(rt1.x,rt1.y); R[3]=mk2(rt1.z,rt1.w);
        R[4]=mk2(rt2.x,rt2.y); R[5]=mk2(rt2.z,rt2.w);
        U[0]=cmul(d,mk2(ct0.x,ct0.y)); U[1]=cmul(d,mk2(ct0.z,ct0.w));
        U[2]=cmul(d,mk2(ct1.x,ct1.y)); U[3]=cmul(d,mk2(ct1.z,ct1.w));
        U[4]=cmul(d,mk2(ct2.x,ct2.y)); U[5]=cmul(d,mk2(ct2.z,ct2.w));
    }
    #pragma unroll 1
    for (int kr=0; kr<8; ++kr){
        #pragma unroll
        for (int kj=0; kj<6; ++kj){
            const int nj   = (kj==5) ? 0 : (kj+1);                 // compile-time
            const int ncr  = (kj==5) ? ((kr<7)?(kr+1):7) : kr;     // runtime (kr)
            const int boff = 24*(nj&1);                            // compile-time dbuf
            const int dsel = nj&1;
            // 1. early update: tile row nj and tile col nj (pivot p's rank-1)
            #pragma unroll
            for (int j=0;j<6;++j) m[nj][j] = cfms(m[nj][j], U[nj], R[j]);
            #pragma unroll
            for (int i=0;i<6;++i){ if (i!=nj) m[i][nj] = cfms(m[i][nj], U[i], R[nj]); }
            // 2. owners publish next pivot's raw row / raw col / raw pivot
            if (lr==ncr){
                #pragma unroll
                for (int jp=0;jp<3;++jp){
                    v2 a = m[nj][2*jp], b = m[nj][2*jp+1];
                    if (lc==ncr){
                        if (2*jp==nj)   a.x += 1.f;   // R'[p'] = pv'+1
                        if (2*jp+1==nj) b.x += 1.f;
                    }
                    v4 t; t.x=a.x; t.y=a.y; t.z=b.x; t.w=b.y;
                    Rb[boff+3*lc+jp] = t;
                }
            }
            if (lc==ncr){
                #pragma unroll
                for (int ip=0;ip<3;++ip){
                    v2 a = m[2*ip][nj], b = m[2*ip+1][nj];
                    if (lr==ncr){
                        if (2*ip==nj)   a.x -= 1.f;   // C'[p'] = pv'-1
                        if (2*ip+1==nj) b.x -= 1.f;
                    }
                    v4 t; t.x=a.x; t.y=a.y; t.z=b.x; t.w=b.y;
                    Cb[boff+3*lr+ip] = t;
                }
                if (lr==ncr) Dp[dsel] = m[nj][nj];
            }
            __builtin_amdgcn_sched_barrier(0);
            // 3. issue read-backs now; data consumed after the bulk update
            v2 pvd = Dp[dsel];
            v4 rt0 = Rb[boff+3*lc+0], rt1 = Rb[boff+3*lc+1], rt2 = Rb[boff+3*lc+2];
            v4 ct0 = Cb[boff+3*lr+0], ct1 = Cb[boff+3*lr+1], ct2 = Cb[boff+3*lr+2];
            __builtin_amdgcn_sched_barrier(0);
            // 4. bulk update: remaining 25 entries (hides LDS read latency)
            #pragma unroll
            for (int i=0;i<6;++i){
                if (i==nj) continue;
                #pragma unroll
                for (int j=0;j<6;++j){
                    if (j==nj) continue;
                    m[i][j] = cfms(m[i][j], U[i], R[j]);
                }
            }
            // 5. unpack + compute next-pivot d', U'
            v2 d = cinv(pvd);
            R[0]=mk2(rt0.x,rt0.y); R[1]=mk2(rt0.z,rt0.w);
            R[2]=mk2(rt1.x,rt1.y); R[3]=mk2(rt1.z,rt1.w);
            R[4]=mk2(rt2.x,rt2.y); R[5]=mk2(rt2.z,rt2.w);
            U[0]=cmul(d,mk2(ct0.x,ct0.y)); U[1]=cmul(d,mk2(ct0.z,ct0.w));
            U[2]=cmul(d,mk2(ct1.x,ct1.y)); U[3]=cmul(d,mk2(ct1.z,ct1.w));
            U[4]=cmul(d,mk2(ct2.x,ct2.y)); U[5]=cmul(d,mk2(ct2.z,ct2.w));
        }
    }
}

__global__ __launch_bounds__(128,1) void helm_babe(
    const float* __restrict__ n_pred,
    const float* __restrict__ xb,
    const float* __restrict__ yaim,
    float*       __restrict__ out,
    int                       out_size,
    float*       __restrict__ wsG)      // 48*2304 cplx (float pairs) G history
{
    __shared__ v2 dgv[NXY], lov[NXY], hiv[NXY];
    __shared__ float nk[NN];            // k^2 n^2 at [iy*48+ix]
    __shared__ float bb[NN];            // b at [iy*48+ix]
    __shared__ v2 zv[NN];               // z/w (fwd) then x, per block
    __shared__ v2 Hx[NN];               // H_25 exchange (wave1 -> wave0)
    __shared__ v2 vv[NXY];              // H_25 * w_25
    __shared__ v4 Rbuf[2][48];          // gj48 row-broadcast, [wave][2 bufs x 24]
    __shared__ v4 Cbuf[2][48];          // gj48 col-broadcast, [wave][2 bufs x 24]
    __shared__ v2 Dbuf[2][2];           // gj48 raw pivot,     [wave][2 bufs]

    const int t    = threadIdx.x;
    const int lane = t & 63;
    const int wid  = t >> 6;            // 0: top sweep, 1: bottom sweep
    const int lr = lane>>3, lc = lane&7;
    const int r0 = 6*lr, c0v = 6*lc;
    const int diagl = (lc<<3)|lc;
    const double k2 = 0.2026833935483871*0.2026833935483871;

    v4* Rb = &Rbuf[wid][0];
    v4* Cb = &Cbuf[wid][0];
    v2* Dp = &Dbuf[wid][0];

    // ---- setup tridiagonal L (fp64 -> fp32) ----
    if (t < NXY){
        int a = t;
        zplx isha  = zinv64(s_half_at(a));
        zplx isha1 = zinv64(s_half_at(a+1));
        zplx isi   = zinv64(s_int_at(a));
        zplx dgd = zneg64(zmul64(isi, zadd64(isha,isha1)));
        zplx lod = zmul64(isi, isha);
        zplx hid = zmul64(isi, isha1);
        dgv[a] = mk2((float)dgd.x,(float)dgd.y);
        lov[a] = mk2((float)lod.x,(float)lod.y);
        hiv[a] = mk2((float)hid.x,(float)hid.y);
    }
    for (int e=t; e<NN; e+=128){
        int i_=e/48, a_=e%48;           // [iy*48+ix] <- input [ix*48+iy]
        float nv = n_pred[a_*48+i_];
        nk[e] = (float)(k2*(double)nv*(double)nv);
        bb[e] = xb[a_*48+i_];
    }
    __syncthreads();

    const int dir    = (wid==0) ? 1 : -1;
    const int ibeg   = (wid==0) ? 0 : 47;
    const int nsteps = (wid==0) ? 25 : 23;   // wave0 step 24 = partial (S_24 only)

    v2 g[6][6];
    v2 m[6][6];
    v2 zrow[6];
    #pragma unroll
    for (int i=0;i<6;++i) zrow[i] = mk2(0.f,0.f);

    // ================= two-sided forward elimination =================
    #pragma unroll 1
    for (int step=0; step<nsteps; ++step){
        int ib = ibeg + dir*step;
        bool full = !(wid==0 && step==24);

        v2 zc[6];
        #pragma unroll
        for (int j=0;j<6;++j) zc[j] = shfl_c(zrow[j], diagl);

        v2 nci = mk2(0.f,0.f), czp = mk2(0.f,0.f);
        if (step>0){
            if (dir>0){ nci = cmul(lov[ib], hiv[ib-1]); czp = lov[ib]; }
            else      { nci = cmul(hiv[ib], lov[ib+1]); czp = hiv[ib]; }
            nci = -nci;
        }
        bool same  = (lc==lr), rightn = (lc==lr+1), leftn = (lc+1==lr);
        v2 p[6];
        #pragma unroll
        for (int i=0;i<6;++i){
            int r = r0+i;
            v2 dgr = dgv[r], lor = lov[r], hir = hiv[r];
            v2 ddi = dgv[ib] + dgr + mk2(nk[ib*48+r],0.f);
            v2 acc = mk2(0.f,0.f);
            #pragma unroll
            for (int j=0;j<6;++j){
                v2 v = (step>0)? cmul(nci, g[i][j]) : mk2(0.f,0.f);
                if (same){
                    if (j==i)   v = v + ddi;
                    if (j==i+1) v = v + hir;
                    if (j+1==i) v = v + lor;
                }
                if (rightn && i==5 && j==0) v = v + hir;
                if (leftn  && i==0 && j==5) v = v + lor;
                m[i][j] = v;
                if (step>0) acc = cfma_(acc, g[i][j], zc[j]);
            }
            p[i] = acc;
        }
        if (step>0){
            #pragma unroll
            for (int i=0;i<6;++i){
                v2 w = bfly_c(p[i]);
                zrow[i] = cfms(mk2(bb[ib*48+r0+i],0.f), czp, w);
            }
        } else {
            #pragma unroll
            for (int i=0;i<6;++i) zrow[i] = mk2(bb[ib*48+r0+i], 0.f);
        }
        if (lc==0){
            #pragma unroll
            for (int i=0;i<6;++i) zv[ib*48+r0+i] = zrow[i];
        }

        if (full){
            gj48_lds(m, lr, lc, Rb, Cb, Dp);
            if (ib == 25){
                #pragma unroll
                for (int i=0;i<6;++i)
                    #pragma unroll
                    for (int j=0;j<6;++j) Hx[(r0+i)*48 + c0v + j] = m[i][j];
            } else {
                #pragma unroll
                for (int i=0;i<6;++i){
                    float4* w4 = (float4*)(wsG + 2*((size_t)ib*NN + (r0+i)*48 + c0v));
                    #pragma unroll
                    for (int jp=0;jp<3;++jp){
                        float4 f;
                        f.x = m[i][2*jp].x;   f.y = m[i][2*jp].y;
                        f.z = m[i][2*jp+1].x; f.w = m[i][2*jp+1].y;
                        w4[jp] = f;
                    }
                }
            }
            #pragma unroll
            for (int i=0;i<6;++i)
                #pragma unroll
                for (int j=0;j<6;++j) g[i][j] = m[i][j];
        }
    }

    // wave 1: v = H_25 * w_25 into LDS
    if (wid==1){
        v2 zc[6];
        #pragma unroll
        for (int j=0;j<6;++j) zc[j] = shfl_c(zrow[j], diagl);
        #pragma unroll
        for (int i=0;i<6;++i){
            v2 acc = mk2(0.f,0.f);
            #pragma unroll
            for (int j=0;j<6;++j) acc = cfma_(acc, m[i][j], zc[j]);
            acc = bfly_c(acc);
            if (lc==0) vv[r0+i] = acc;
        }
    }
    __syncthreads();

    // ================= interface (wave 0) =================
    v2 xrow[6];
    if (wid==0){
        // m = S_24, zrow = z_24 (valid all lanes)
        v2 cf = cmul(hiv[24], lov[25]);
        #pragma unroll
        for (int i=0;i<6;++i)
            #pragma unroll
            for (int j=0;j<6;++j) m[i][j] = cfms(m[i][j], cf, Hx[(r0+i)*48 + c0v + j]);
        #pragma unroll
        for (int i=0;i<6;++i) zrow[i] = cfms(zrow[i], hiv[24], vv[r0+i]);
        gj48_lds(m, lr, lc, Rb, Cb, Dp);    // m = F^{-1}
        v2 zc[6];
        #pragma unroll
        for (int j=0;j<6;++j) zc[j] = shfl_c(zrow[j], diagl);
        #pragma unroll
        for (int i=0;i<6;++i){
            v2 acc = mk2(0.f,0.f);
            #pragma unroll
            for (int j=0;j<6;++j) acc = cfma_(acc, m[i][j], zc[j]);
            xrow[i] = bfly_c(acc);
        }
        if (lc==0){
            #pragma unroll
            for (int i=0;i<6;++i) zv[24*48+r0+i] = xrow[i];
        }
        // x_25 = H_25 (w_25 - lov[25] x_24)
        v2 xc[6], tm[6];
        #pragma unroll
        for (int j=0;j<6;++j) xc[j] = shfl_c(xrow[j], diagl);
        #pragma unroll
        for (int j=0;j<6;++j) tm[j] = cfms(zv[25*48+c0v+j], lov[25], xc[j]);
        #pragma unroll
        for (int i=0;i<6;++i){
            v2 acc = mk2(0.f,0.f);
            #pragma unroll
            for (int j=0;j<6;++j) acc = cfma_(acc, Hx[(r0+i)*48 + c0v + j], tm[j]);
            acc = bfly_c(acc);
            if (lc==0) zv[25*48+r0+i] = acc;
        }
    }
    __syncthreads();

    // ================= parallel back-substitution =================
    if (wid==0){
        #pragma unroll 1
        for (int ib=23; ib>=0; --ib){
            v2 xc[6], tm[6];
            #pragma unroll
            for (int j=0;j<6;++j) xc[j] = shfl_c(xrow[j], diagl);
            v2 hiib = hiv[ib];
            #pragma unroll
            for (int j=0;j<6;++j) tm[j] = cfms(zv[ib*48+c0v+j], hiib, xc[j]);
            #pragma unroll
            for (int i=0;i<6;++i){
                const float4* w4 = (const float4*)(wsG + 2*((size_t)ib*NN + (r0+i)*48 + c0v));
                v2 acc = mk2(0.f,0.f);
                #pragma unroll
                for (int jp=0;jp<3;++jp){
                    float4 f = w4[jp];
                    acc = cfma_(acc, mk2(f.x,f.y), tm[2*jp]);
                    acc = cfma_(acc, mk2(f.z,f.w), tm[2*jp+1]);
                }
                xrow[i] = bfly_c(acc);
            }
            if (lc==0){
                #pragma unroll
                for (int i=0;i<6;++i) zv[ib*48+r0+i] = xrow[i];
            }
        }
    } else {
        #pragma unroll
        for (int i=0;i<6;++i) xrow[i] = zv[25*48+r0+i];
        #pragma unroll 1
        for (int ib=26; ib<NXY; ++ib){
            v2 xc[6], tm[6];
            #pragma unroll
            for (int j=0;j<6;++j) xc[j] = shfl_c(xrow[j], diagl);
            v2 loib = lov[ib];
            #pragma unroll
            for (int j=0;j<6;++j) tm[j] = cfms(zv[ib*48+c0v+j], loib, xc[j]);
            #pragma unroll
            for (int i=0;i<6;++i){
                const float4* w4 = (const float4*)(wsG + 2*((size_t)ib*NN + (r0+i)*48 + c0v));
                v2 acc = mk2(0.f,0.f);
                #pragma unroll
                for (int jp=0;jp<3;++jp){
                    float4 f = w4[jp];
                    acc = cfma_(acc, mk2(f.x,f.y), tm[2*jp]);
                    acc = cfma_(acc, mk2(f.z,f.w), tm[2*jp+1]);
                }
                xrow[i] = bfly_c(acc);
            }
            if (lc==0){
                #pragma unroll
                for (int i=0;i<6;++i) zv[ib*48+r0+i] = xrow[i];
            }
        }
    }
    __syncthreads();

    // ================= epilogue =================
    for (int e=t; e<NN; e+=128){
        int alpha=e/48, beta=e%48;
        v2 psi = zv[beta*48+alpha];
        float y0=yaim[2*e], y1=yaim[2*e+1];
        if (out_size == NN*4){
            float4 o = make_float4(psi.x*y0, psi.x*y1, y0*y0, y1*y1);
            *(float4*)(out + 4*e) = o;
        } else {
            float* o = out + 8*e;
            o[0]=psi.x*y0; o[1]=psi.y*y0; o[2]=psi.x*y1; o[3]=psi.y*y1;
            o[4]=y0*y0; o[5]=0.f; o[6]=y1*y1; o[7]=0.f;
        }
    }
}

extern "C" void kernel_launch(void* const* d_in, const int* in_sizes, int n_in,
                              void* d_out, int out_size, void* d_ws, size_t ws_size,
                              hipStream_t stream) {
    const float* n_pred = (const float*)d_in[0];   // n_prediction
    const float* xb     = (const float*)d_in[2];   // x_b
    const float* ya     = (const float*)d_in[3];   // y_aim
    float* out = (float*)d_out;
    float* wsG = (float*)d_ws;                     // 48*2304*8 = 884736 B

    hipLaunchKernelGGL(helm_babe, dim3(1), dim3(128), 0, stream,
                       n_pred, xb, ya, out, out_size, wsG);
}